// Round 4
// baseline (965.607 us; speedup 1.0000x reference)
//
#include <hip/hip_runtime.h>
#include <math.h>

#define N_NODES 231
#define N_EDGES 1848
#define TOT_E   (N_EDGES + N_NODES)   // 2079 incl. self loops
#define NTS     256                   // setup block
#define NT      1024                  // fused block (16 waves)
#define GB      8                     // graphs per block (= lane batch dim)

__device__ __forceinline__ float fast_tanh(float x) {
    float e = __expf(2.f * x);
    return 1.f - 2.f * __builtin_amdgcn_rcpf(e + 1.f);
}
__device__ __forceinline__ float elu(float v) {
    return v > 0.f ? v : __expf(v) - 1.f;
}

// ---------------- setup: dst-CSR with packed {src, norm} ------------------
__global__ void gcn_setup(const int* __restrict__ ei,
                          int* __restrict__ offs,      // [232]
                          int2* __restrict__ epack) {  // [TOT_E + 1]
    __shared__ int   deg[N_NODES];
    __shared__ float invs[N_NODES];
    __shared__ int   soffs[N_NODES + 1];
    __shared__ int   fill[N_NODES];
    const int tid = threadIdx.x;
    for (int i = tid; i < N_NODES; i += NTS) { deg[i] = 1; fill[i] = 0; }
    __syncthreads();
    for (int e = tid; e < N_EDGES; e += NTS)
        atomicAdd(&deg[ei[N_EDGES + e]], 1);
    __syncthreads();
    if (tid == 0) {
        int acc = 0;
        for (int i = 0; i < N_NODES; ++i) { soffs[i] = acc; acc += deg[i]; }
        soffs[N_NODES] = acc;  // == TOT_E
    }
    __syncthreads();
    for (int i = tid; i < N_NODES; i += NTS) invs[i] = rsqrtf((float)deg[i]);
    __syncthreads();
    for (int e = tid; e < N_EDGES; e += NTS) {
        int s = ei[e], d = ei[N_EDGES + e];
        int p = soffs[d] + atomicAdd(&fill[d], 1);
        epack[p] = make_int2(s, __float_as_int(invs[s] * invs[d]));
    }
    for (int i = tid; i < N_NODES; i += NTS) {
        int p = soffs[i] + atomicAdd(&fill[i], 1);
        epack[p] = make_int2(i, __float_as_int(invs[i] * invs[i]));
    }
    __syncthreads();
    for (int i = tid; i <= N_NODES; i += NTS) offs[i] = soffs[i];
    if (tid == 0) epack[TOT_E] = make_int2(0, 0);   // prefetch pad
}

// ------------- fused GCNx3 + FCx3, batch-in-lanes layout ------------------
// LDS: sT1 [231][8][8] f32 (node-row = 64 consecutive floats)
//      sT2 [231][4][8]; reused as H3 [462][8] / z1 [120][9] / z2 [84][9]
__global__ __launch_bounds__(NT)
void gcn_fused(const float* __restrict__ x,
               const int* __restrict__ goffs,
               const int2* __restrict__ epk,
               const float* __restrict__ W1, const float* __restrict__ b1,
               const float* __restrict__ W2, const float* __restrict__ b2,
               const float* __restrict__ W3, const float* __restrict__ b3,
               const float* __restrict__ Wf1, const float* __restrict__ bf1,
               const float* __restrict__ Wf2, const float* __restrict__ bf2,
               const float* __restrict__ Wf3, const float* __restrict__ bf3,
               float* __restrict__ out, int B) {
    __shared__ float sT1[N_NODES * 64];   // 59.1 KB
    __shared__ float sT2[7392];           // 29.6 KB
    __shared__ float sWc[152];            // W1|b1|W2|b2|W3|b3

    const int tid  = threadIdx.x;
    const int lane = tid & 63;
    const int wid  = __builtin_amdgcn_readfirstlane(tid >> 6);
    const int g0   = blockIdx.x * GB;

    if (tid < 96)       sWc[tid] = W1[tid];
    else if (tid < 104) sWc[tid] = b1[tid - 96];
    else if (tid < 136) sWc[tid] = W2[tid - 104];
    else if (tid < 140) sWc[tid] = b2[tid - 136];
    else if (tid < 148) sWc[tid] = W3[tid - 140];
    else if (tid < 150) sWc[tid] = b3[tid - 148];
    __syncthreads();

    // ---- transform-1: t1 = x @ W1, write [n][k][b] ----
    for (int t = tid; t < N_NODES * GB; t += NT) {
        int n = t >> 3, b = t & 7;
        int gid = g0 + b; if (gid >= B) gid = B - 1;
        const float4* xp = (const float4*)(x + ((size_t)gid * N_NODES + n) * 12);
        float4 a = xp[0], c = xp[1], d = xp[2];
        float xr[12] = {a.x,a.y,a.z,a.w, c.x,c.y,c.z,c.w, d.x,d.y,d.z,d.w};
        float t1[8];
#pragma unroll
        for (int k = 0; k < 8; ++k) t1[k] = 0.f;
#pragma unroll
        for (int f = 0; f < 12; ++f) {
            float xv = xr[f];
#pragma unroll
            for (int k = 0; k < 8; ++k) t1[k] = fmaf(xv, sWc[f*8 + k], t1[k]);
        }
#pragma unroll
        for (int k = 0; k < 8; ++k) sT1[n*64 + k*8 + b] = t1[k];
    }
    __syncthreads();

    // ---- agg-1 (wave = 1 node, 8k x 8b lanes) + tanh + @W2 -> sT2 ----
    {
        const int kk = lane >> 3, bb = lane & 7;
        for (int n = wid; n < N_NODES; n += 16) {
            const int e0 = goffs[n], e1 = goffs[n + 1];
            float acc = 0.f;
            int2 ep = epk[e0];
            for (int e = e0; e < e1; ++e) {
                int2 nxt = epk[e + 1];                       // prefetch (padded)
                acc = fmaf(__int_as_float(ep.y), sT1[ep.x*64 + lane], acc);
                ep = nxt;
            }
            float h1 = fast_tanh(acc + sWc[96 + kk]);
            float v0 = h1 * sWc[104 + kk*4 + 0];
            float v1 = h1 * sWc[104 + kk*4 + 1];
            float v2 = h1 * sWc[104 + kk*4 + 2];
            float v3 = h1 * sWc[104 + kk*4 + 3];
#pragma unroll
            for (int m = 8; m < 64; m <<= 1) {               // reduce over k lanes
                v0 += __shfl_xor(v0, m);
                v1 += __shfl_xor(v1, m);
                v2 += __shfl_xor(v2, m);
                v3 += __shfl_xor(v3, m);
            }
            if (kk < 4) {
                float v = kk == 0 ? v0 : (kk == 1 ? v1 : (kk == 2 ? v2 : v3));
                sT2[n*32 + kk*8 + bb] = v;
            }
        }
    }
    __syncthreads();

    // ---- agg-2 (wave = 2 adjacent nodes, union CSR range) + tanh + @W3 -> T3 (in sT1) ----
    {
        const bool half0 = (lane >> 5) == 0;
        const int  cc = (lane >> 3) & 3, bb = lane & 7, l31 = lane & 31;
        for (int pi = wid; pi < 116; pi += 16) {
            const int n0 = pi * 2;
            const int n1c = n0 + 1 < N_NODES ? n0 + 1 : N_NODES;
            const int n2c = n0 + 2 < N_NODES ? n0 + 2 : N_NODES;
            const int eLo = goffs[n0], eMid = goffs[n1c], eHi = goffs[n2c];
            float acc = 0.f;
            int2 ep = epk[eLo];
            for (int e = eLo; e < eHi; ++e) {
                int2 nxt = epk[e + 1];
                float w = ((e < eMid) == half0) ? __int_as_float(ep.y) : 0.f;
                acc = fmaf(w, sT2[ep.x*32 + l31], acc);
                ep = nxt;
            }
            float h2 = fast_tanh(acc + sWc[136 + cc]);
            float v0 = h2 * sWc[140 + cc*2 + 0];
            float v1 = h2 * sWc[140 + cc*2 + 1];
            v0 += __shfl_xor(v0, 8);  v1 += __shfl_xor(v1, 8);
            v0 += __shfl_xor(v0, 16); v1 += __shfl_xor(v1, 16);
            const int n = n0 + (half0 ? 0 : 1);
            if (cc < 2 && n < N_NODES)
                sT1[n*16 + cc*8 + bb] = (cc == 0 ? v0 : v1);
        }
    }
    __syncthreads();

    // ---- agg-3 (wave = 4 adjacent nodes) + b3 -> H3 [462][8] in sT2 ----
    {
        const int q = lane >> 4, dd = (lane >> 3) & 1, bb = lane & 7, l15 = lane & 15;
        for (int qi = wid; qi < 58; qi += 16) {
            const int n0 = qi * 4;
            const int c1 = n0+1 < N_NODES ? n0+1 : N_NODES;
            const int c2 = n0+2 < N_NODES ? n0+2 : N_NODES;
            const int c3 = n0+3 < N_NODES ? n0+3 : N_NODES;
            const int c4 = n0+4 < N_NODES ? n0+4 : N_NODES;
            const int eB0 = goffs[n0], eB1 = goffs[c1], eB2 = goffs[c2],
                      eB3 = goffs[c3], eB4 = goffs[c4];
            float acc = 0.f;
            int2 ep = epk[eB0];
            for (int e = eB0; e < eB4; ++e) {
                int2 nxt = epk[e + 1];
                int owner = (e >= eB1) + (e >= eB2) + (e >= eB3);
                float w = (owner == q) ? __int_as_float(ep.y) : 0.f;
                acc = fmaf(w, sT1[ep.x*16 + l15], acc);
                ep = nxt;
            }
            const int n = n0 + q;
            if (n < N_NODES)
                sT2[(n*2 + dd)*8 + bb] = acc + sWc[148 + dd];
        }
    }
    __syncthreads();

    // ---- FC1: z1[j][g] = elu(h3 . Wf1[:,j] + bf1) ----
    if (tid < 960) {
        const int g = tid / 120, j = tid - g * 120;
        float acc = bf1[j];
#pragma unroll 4
        for (int i = 0; i < 462; ++i)
            acc = fmaf(sT2[i*8 + g], Wf1[i*120 + j], acc);
        sT2[4096 + j*9 + g] = elu(acc);
    }
    __syncthreads();

    // ---- FC2 ----
    if (tid < 672) {
        const int g = tid / 84, j = tid - g * 84;
        float acc = bf2[j];
#pragma unroll 4
        for (int i = 0; i < 120; ++i)
            acc = fmaf(sT2[4096 + i*9 + g], Wf2[i*84 + j], acc);
        sT2[5632 + j*9 + g] = elu(acc);
    }
    __syncthreads();

    // ---- FC3 + store ----
    if (tid < 80) {
        const int g = tid / 10, j = tid - g * 10;
        float acc = bf3[j];
#pragma unroll 4
        for (int i = 0; i < 84; ++i)
            acc = fmaf(sT2[5632 + i*9 + g], Wf3[i*10 + j], acc);
        if (g0 + g < B) out[(size_t)(g0 + g) * 10 + j] = acc;
    }
}

extern "C" void kernel_launch(void* const* d_in, const int* in_sizes, int n_in,
                              void* d_out, int out_size, void* d_ws, size_t ws_size,
                              hipStream_t stream) {
    const float* x   = (const float*)d_in[0];
    const int*   ei  = (const int*)d_in[1];
    const float* W1  = (const float*)d_in[2];
    const float* b1  = (const float*)d_in[3];
    const float* W2  = (const float*)d_in[4];
    const float* b2  = (const float*)d_in[5];
    const float* W3  = (const float*)d_in[6];
    const float* b3  = (const float*)d_in[7];
    const float* Wf1 = (const float*)d_in[8];
    const float* bf1 = (const float*)d_in[9];
    const float* Wf2 = (const float*)d_in[10];
    const float* bf2 = (const float*)d_in[11];
    const float* Wf3 = (const float*)d_in[12];
    const float* bf3 = (const float*)d_in[13];
    float* out = (float*)d_out;

    const int B = in_sizes[0] / (N_NODES * 12);

    // ws: offs @0 (1 KB) | epack @1024 (16.7 KB)
    int*  offs  = (int*)d_ws;
    int2* epack = (int2*)((char*)d_ws + 1024);

    gcn_setup<<<1, NTS, 0, stream>>>(ei, offs, epack);
    gcn_fused<<<(B + GB - 1) / GB, NT, 0, stream>>>(
        x, offs, epack,
        W1, b1, W2, b2, W3, b3,
        Wf1, bf1, Wf2, bf2, Wf3, bf3, out, B);
}